// Round 1
// baseline (1193.338 us; speedup 1.0000x reference)
//
#include <hip/hip_runtime.h>
#include <stdint.h>

typedef unsigned short u16;
typedef unsigned int u32;
typedef __attribute__((ext_vector_type(8))) short short8;   // 8 x bf16 (4 VGPRs)
typedef __attribute__((ext_vector_type(4))) float f32x4;

#define DEVI static __device__ __forceinline__

#define S_LEN 2048
#define DMODEL 1024
#define NHEAD 16
#define DK 64
#define NEG_INF (-__builtin_inff())
// u = bitcast((bits>>9)|0x3f800000)-1; boundary 0.9f = 7549747/2^23
// keep:   u > 0.9  <=> bits >= 7549748*512
// dropout keep: u < 0.9  <=> bits <  7549747*512
#define KEEPC 3865470976u
#define DROPC 3865470464u

DEVI u16 f2bf(float f) {
  u32 u = __builtin_bit_cast(u32, f);
  u32 r = u + 0x7fffu + ((u >> 16) & 1u);   // RNE
  return (u16)(r >> 16);
}

DEVI short8 cvt8(float4 a, float4 b) {
  short8 r;
  r[0] = (short)f2bf(a.x); r[1] = (short)f2bf(a.y);
  r[2] = (short)f2bf(a.z); r[3] = (short)f2bf(a.w);
  r[4] = (short)f2bf(b.x); r[5] = (short)f2bf(b.y);
  r[6] = (short)f2bf(b.z); r[7] = (short)f2bf(b.w);
  return r;
}

// JAX threefry2x32 (20 rounds), partitionable draw (default since jax 0.4.36):
// key (0,key), ctr (0,i), bits = o0 ^ o1. key is compile-time const at call
// sites -> K2 and injections fold. Validated bit-exact in rounds 2/3.
DEVI u32 tf_bits(u32 key, u32 i) {
  const u32 K2 = key ^ 0x1BD11BDAu;
  u32 x0 = 0u, x1 = i + key;
#define TFR(r) { x0 += x1; x1 = __builtin_rotateleft32(x1, r); x1 ^= x0; }
  TFR(13) TFR(15) TFR(26) TFR(6)  x0 += key; x1 += K2 + 1u;
  TFR(17) TFR(29) TFR(16) TFR(24) x0 += K2;  x1 += 2u;
  TFR(13) TFR(15) TFR(26) TFR(6)  /*x0+=0*/  x1 += key + 3u;
  TFR(17) TFR(29) TFR(16) TFR(24) x0 += key; x1 += K2 + 4u;
  TFR(13) TFR(15) TFR(26) TFR(6)  x0 += K2;  x1 += 5u;
#undef TFR
  return x0 ^ x1;
}

// ---------------- QKV projection GEMM (x @ W.T + b), fp32 in, bf16 MFMA ----------------
// 64x64 tile / block, 4 waves (2x2), each wave 32x32 via 4 C-frags.
// LDS frag-major: chunk c = fragblk*64+lane holds T[row=fragblk*16+(lane&15)][k=(lane>>4)*8..+7]
__global__ __launch_bounds__(256) void proj_kernel(
    const float* __restrict__ Xq, const float* __restrict__ Xk, const float* __restrict__ Xv,
    const float* __restrict__ Wq, const float* __restrict__ Wk, const float* __restrict__ Wv,
    const float* __restrict__ bq, const float* __restrict__ bk, const float* __restrict__ bv,
    u16* __restrict__ Qo, u16* __restrict__ Ko, u16* __restrict__ Vto)
{
  const int z = blockIdx.z;
  const float* X = (z == 0) ? Xq : (z == 1) ? Xk : Xv;
  const float* W = (z == 0) ? Wq : (z == 1) ? Wk : Wv;
  const float* bias = (z == 0) ? bq : (z == 1) ? bk : bv;
  const int m0 = blockIdx.x * 64, n0 = blockIdx.y * 64;
  const int tid = threadIdx.x, w = tid >> 6, lane = tid & 63, l = lane & 15, quad = lane >> 4;

  __shared__ __align__(16) u16 lsA[2048], lsB[2048];

  const int srow = tid >> 2, skp = tid & 3;
  const int sc = ((srow >> 4) * 64 + skp * 16 + (srow & 15)) * 8;
  const float* gA = X + (u32)(m0 + srow) * DMODEL + skp * 8;
  const float* gB = W + (u32)(n0 + srow) * DMODEL + skp * 8;

  f32x4 acc[2][2] = {};
  const int mh = (w >> 1) * 2, nh = (w & 1) * 2;

  for (int k0 = 0; k0 < DMODEL; k0 += 32) {
    short8 av  = cvt8(*(const float4*)(gA + k0), *(const float4*)(gA + k0 + 4));
    short8 bv8 = cvt8(*(const float4*)(gB + k0), *(const float4*)(gB + k0 + 4));
    __syncthreads();
    *(short8*)(lsA + sc) = av;
    *(short8*)(lsB + sc) = bv8;
    __syncthreads();
    short8 a0 = *(const short8*)(lsA + ((mh + 0) * 64 + lane) * 8);
    short8 a1 = *(const short8*)(lsA + ((mh + 1) * 64 + lane) * 8);
    short8 b0 = *(const short8*)(lsB + ((nh + 0) * 64 + lane) * 8);
    short8 b1 = *(const short8*)(lsB + ((nh + 1) * 64 + lane) * 8);
    acc[0][0] = __builtin_amdgcn_mfma_f32_16x16x32_bf16(a0, b0, acc[0][0], 0, 0, 0);
    acc[0][1] = __builtin_amdgcn_mfma_f32_16x16x32_bf16(a0, b1, acc[0][1], 0, 0, 0);
    acc[1][0] = __builtin_amdgcn_mfma_f32_16x16x32_bf16(a1, b0, acc[1][0], 0, 0, 0);
    acc[1][1] = __builtin_amdgcn_mfma_f32_16x16x32_bf16(a1, b1, acc[1][1], 0, 0, 0);
  }

  #pragma unroll
  for (int ma = 0; ma < 2; ++ma) {
    #pragma unroll
    for (int nb = 0; nb < 2; ++nb) {
      const int n = n0 + (nh + nb) * 16 + l;
      const float bval = bias[n];
      const int h = n >> 6, d = n & 63;
      #pragma unroll
      for (int r = 0; r < 4; ++r) {
        const int m = m0 + (mh + ma) * 16 + quad * 4 + r;
        float val = acc[ma][nb][r] + bval;
        if (z == 0) val *= 0.125f;              // fold 1/sqrt(dk) into Q
        const int b = m >> 11, s = m & 2047;
        if (z == 0)      Qo [((u32)(b * NHEAD + h) * S_LEN + s) * DK + d] = f2bf(val);
        else if (z == 1) Ko [((u32)(b * NHEAD + h) * S_LEN + s) * DK + d] = f2bf(val);
        else             Vto[((u32)(b * NHEAD + h) * DK + d) * S_LEN + s] = f2bf(val); // V transposed
      }
    }
  }
}

// ---------------- flash attention with INLINE threefry mask + dropout ----------------
// Masks are generated per-lane in exactly the MFMA C-layout positions this lane
// owns: rows quad*4+r, cols c*16+(lane&15). Draw index i = (bh*2048+q)*2048+k.
// Bit s = c*4+r in m16/d16. No mask memory traffic, no cross-lane machinery.
//
// LDS plan (16 KB -> 8 blocks/CU, single dispatch round):
//   KPf: K frags during QK^T; after a barrier the SAME region is reused as
//        per-wave P staging (K is fully consumed into sc4 by then).
//   P addresses are XOR-swizzled (bit3 ^= quad>>1, bit4 ^= hi, u16 units) so
//   all 5 bank bits carry independent lane bits -> conflict-free b16 writes;
//   reads apply the same swizzle via (lane*8) ^ (lane & 24), 16B-granular.
__global__ __launch_bounds__(256, 8) void attn_kernel(
    const u16* __restrict__ Qs, const u16* __restrict__ Ks, const u16* __restrict__ Vts,
    u16* __restrict__ ctx)
{
  const int qb = blockIdx.x, bh = blockIdx.y;
  const int tid = threadIdx.x, w = tid >> 6, lane = tid & 63, l = lane & 15, quad = lane >> 4;

  __shared__ __align__(16) u16 KPf[4096];       // 8 KB: K frags, then per-wave P
  __shared__ __align__(16) u16 Vf[4096];        // 8 KB

  // Q A-frags, preloaded (Q pre-scaled by 1/8)
  const int qrow0 = qb * 64 + w * 16;
  const u32 qbase = (u32)(bh * S_LEN + qrow0 + l) * DK + quad * 8;
  const short8 qa0 = *(const short8*)(Qs + qbase);
  const short8 qa1 = *(const short8*)(Qs + qbase + 32);

  // per-lane RNG base: rows start at qrow0+quad*4, col offset l (within tile)
  u32 ibase = ((u32)bh * 2048u + (u32)(qrow0 + quad * 4)) * 2048u + (u32)l;

  f32x4 o[4] = {};
  float mr[4] = {NEG_INF, NEG_INF, NEG_INF, NEG_INF};
  float lr[4] = {0.f, 0.f, 0.f, 0.f};

  // staging maps (2 chunks per thread per tile), globally coalesced
  const int tA = tid, tB = tid + 256;
  const int keyA = tA >> 3, dpA = tA & 7;
  const int kcA = (((dpA >> 2) * 4 + (keyA >> 4)) * 64 + (dpA & 3) * 16 + (keyA & 15)) * 8;
  const u32 gkA = (u32)(bh * S_LEN + keyA) * DK + dpA * 8;
  const int keyB = tB >> 3, dpB = tB & 7;
  const int kcB = (((dpB >> 2) * 4 + (keyB >> 4)) * 64 + (dpB & 3) * 16 + (keyB & 15)) * 8;
  const u32 gkB = (u32)(bh * S_LEN + keyB) * DK + dpB * 8;
  const int vcA = (((keyA >> 4) * 2 + (dpA >> 2)) * 64 + (dpA & 3) * 16 + (keyA & 15)) * 8;
  const u32 gvA = (u32)(bh * DK + keyA) * S_LEN + dpA * 8;   // keyA plays "d" role here
  const int vcB = (((keyB >> 4) * 2 + (dpB >> 2)) * 64 + (dpB & 3) * 16 + (keyB & 15)) * 8;
  const u32 gvB = (u32)(bh * DK + keyB) * S_LEN + dpB * 8;

  // P staging addresses (swizzled). Write chunk c = kb*16 + (quad*4+r):
  //   u16 idx = c*8 + j, with idx bit3 ^= (quad>>1), bit4 ^= hi (hi = kb&1 = l>>3).
  const int hi = l >> 3, j = l & 7;
  const int pxor = ((quad >> 1) << 3) | (hi << 4);
  const int pb = (hi * 128 + quad * 32 + j) ^ pxor;     // r==0 base; bits 3,4 free for r
  const int prd = (lane * 8) ^ (lane & 24);             // swizzled read chunk offset
  u16* const pw = KPf + w * 1024;

  for (int kt = 0; kt < 32; ++kt) {
    const u32 ko = (u32)kt * 64u;
    short8 k0v = *(const short8*)(Ks + gkA + ko * DK);
    short8 k1v = *(const short8*)(Ks + gkB + ko * DK);
    short8 v0v = *(const short8*)(Vts + gvA + ko);
    short8 v1v = *(const short8*)(Vts + gvB + ko);

    // ---- inline RNG: 16 independent keep draws (ILP), then sparse dropout ----
    u32 m16 = 0;
    #pragma unroll
    for (int c = 0; c < 4; ++c) {
      #pragma unroll
      for (int r = 0; r < 4; ++r) {
        m16 |= (u32)(tf_bits(42u, ibase + (u32)(r * 2048 + c * 16)) >= KEEPC) << (c * 4 + r);
      }
    }
    u32 d16 = 0, mm = m16;
    while (mm) {
      const u32 s = (u32)__builtin_ctz(mm); mm &= mm - 1u;
      const u32 ii = ibase + (s & 3u) * 2048u + (s >> 2) * 16u;
      d16 |= (u32)(tf_bits(7u, ii) < DROPC) << s;
    }
    ibase += 64u;

    __syncthreads();                    // prev iter's P/V reads done
    *(short8*)(KPf + kcA) = k0v;
    *(short8*)(KPf + kcB) = k1v;
    *(short8*)(Vf + vcA) = v0v;
    *(short8*)(Vf + vcB) = v1v;
    __syncthreads();

    // S = Q K^T (16q x 64keys per wave)
    f32x4 sc4[4];
    #pragma unroll
    for (int nc = 0; nc < 4; ++nc) {
      short8 kb0 = *(const short8*)(KPf + (nc * 64 + lane) * 8);
      short8 kb1 = *(const short8*)(KPf + ((4 + nc) * 64 + lane) * 8);
      f32x4 zz = {0.f, 0.f, 0.f, 0.f};
      zz = __builtin_amdgcn_mfma_f32_16x16x32_bf16(qa0, kb0, zz, 0, 0, 0);
      sc4[nc] = __builtin_amdgcn_mfma_f32_16x16x32_bf16(qa1, kb1, sc4[nc] = zz, 0, 0, 0);
    }

    __syncthreads();                    // K fully consumed -> KPf reusable as P

    #pragma unroll
    for (int r = 0; r < 4; ++r) {
      float v0 = ((m16 >> (r + 0))  & 1u) ? sc4[0][r] : NEG_INF;
      float v1 = ((m16 >> (r + 4))  & 1u) ? sc4[1][r] : NEG_INF;
      float v2 = ((m16 >> (r + 8))  & 1u) ? sc4[2][r] : NEG_INF;
      float v3 = ((m16 >> (r + 12)) & 1u) ? sc4[3][r] : NEG_INF;
      float mx = fmaxf(fmaxf(v0, v1), fmaxf(v2, v3));
      mx = fmaxf(mx, __shfl_xor(mx, 1));
      mx = fmaxf(mx, __shfl_xor(mx, 2));
      mx = fmaxf(mx, __shfl_xor(mx, 4));
      mx = fmaxf(mx, __shfl_xor(mx, 8));
      const float mn = fmaxf(mr[r], mx);
      const float alpha = (mn == NEG_INF) ? 1.f : __expf(mr[r] - mn);
      mr[r] = mn;
      const float p0 = (v0 == NEG_INF) ? 0.f : __expf(v0 - mn);
      const float p1 = (v1 == NEG_INF) ? 0.f : __expf(v1 - mn);
      const float p2 = (v2 == NEG_INF) ? 0.f : __expf(v2 - mn);
      const float p3 = (v3 == NEG_INF) ? 0.f : __expf(v3 - mn);
      float rs = p0 + p1 + p2 + p3;
      rs += __shfl_xor(rs, 1);
      rs += __shfl_xor(rs, 2);
      rs += __shfl_xor(rs, 4);
      rs += __shfl_xor(rs, 8);
      lr[r] = alpha * lr[r] + rs;
      o[0][r] = o[0][r] * alpha; o[1][r] = o[1][r] * alpha;
      o[2][r] = o[2][r] * alpha; o[3][r] = o[3][r] * alpha;
      // dropout (denominator uses undropped p; numerator uses p*dbit/0.9)
      const float pd0 = ((d16 >> (r + 0))  & 1u) ? p0 * (1.f / 0.9f) : 0.f;
      const float pd1 = ((d16 >> (r + 4))  & 1u) ? p1 * (1.f / 0.9f) : 0.f;
      const float pd2 = ((d16 >> (r + 8))  & 1u) ? p2 * (1.f / 0.9f) : 0.f;
      const float pd3 = ((d16 >> (r + 12)) & 1u) ? p3 * (1.f / 0.9f) : 0.f;
      // write P in A-frag layout (bank-conflict-free via XOR swizzle)
      const int pi = pb ^ (r * 8);
      pw[pi      ] = f2bf(pd0);   // keys  0..15
      pw[pi + 256] = f2bf(pd1);   // keys 16..31
      pw[pi + 512] = f2bf(pd2);   // keys 32..47
      pw[pi + 768] = f2bf(pd3);   // keys 48..63
    }
    // same-wave LDS round-trip: read P as A-frags (swizzled chunk order)
    short8 pa0 = *(const short8*)(pw + prd);
    short8 pa1 = *(const short8*)(pw + 512 + prd);
    #pragma unroll
    for (int nd = 0; nd < 4; ++nd) {
      short8 vb0 = *(const short8*)(Vf + ((nd * 2 + 0) * 64 + lane) * 8);
      short8 vb1 = *(const short8*)(Vf + ((nd * 2 + 1) * 64 + lane) * 8);
      o[nd] = __builtin_amdgcn_mfma_f32_16x16x32_bf16(pa0, vb0, o[nd], 0, 0, 0);
      o[nd] = __builtin_amdgcn_mfma_f32_16x16x32_bf16(pa1, vb1, o[nd], 0, 0, 0);
    }
  }

  const int b = bh >> 4, h = bh & 15;
  #pragma unroll
  for (int r = 0; r < 4; ++r) {
    const float inv = 1.f / lr[r];
    const int qrow = qb * 64 + w * 16 + quad * 4 + r;
    const u32 ob = (u32)(b * S_LEN + qrow) * DMODEL + h * DK;
    ctx[ob + 0  + l] = f2bf(o[0][r] * inv);
    ctx[ob + 16 + l] = f2bf(o[1][r] * inv);
    ctx[ob + 32 + l] = f2bf(o[2][r] * inv);
    ctx[ob + 48 + l] = f2bf(o[3][r] * inv);
  }
}

// ---------------- output projection (ctx @ Wo.T + bo), bf16 A, fp32 B-in, fp32 out ----------------
__global__ __launch_bounds__(256) void oproj_kernel(
    const u16* __restrict__ X, const float* __restrict__ W, const float* __restrict__ bias,
    float* __restrict__ out)
{
  const int m0 = blockIdx.x * 64, n0 = blockIdx.y * 64;
  const int tid = threadIdx.x, w = tid >> 6, lane = tid & 63, l = lane & 15, quad = lane >> 4;

  __shared__ __align__(16) u16 lsA[2048], lsB[2048];

  const int srow = tid >> 2, skp = tid & 3;
  const int sc = ((srow >> 4) * 64 + skp * 16 + (srow & 15)) * 8;
  const u16*  gA = X + (u32)(m0 + srow) * DMODEL + skp * 8;
  const float* gB = W + (u32)(n0 + srow) * DMODEL + skp * 8;

  f32x4 acc[2][2] = {};
  const int mh = (w >> 1) * 2, nh = (w & 1) * 2;

  for (int k0 = 0; k0 < DMODEL; k0 += 32) {
    short8 av  = *(const short8*)(gA + k0);
    short8 bv8 = cvt8(*(const float4*)(gB + k0), *(const float4*)(gB + k0 + 4));
    __syncthreads();
    *(short8*)(lsA + sc) = av;
    *(short8*)(lsB + sc) = bv8;
    __syncthreads();
    short8 a0 = *(const short8*)(lsA + ((mh + 0) * 64 + lane) * 8);
    short8 a1 = *(const short8*)(lsA + ((mh + 1) * 64 + lane) * 8);
    short8 b0 = *(const short8*)(lsB + ((nh + 0) * 64 + lane) * 8);
    short8 b1 = *(const short8*)(lsB + ((nh + 1) * 64 + lane) * 8);
    acc[0][0] = __builtin_amdgcn_mfma_f32_16x16x32_bf16(a0, b0, acc[0][0], 0, 0, 0);
    acc[0][1] = __builtin_amdgcn_mfma_f32_16x16x32_bf16(a0, b1, acc[0][1], 0, 0, 0);
    acc[1][0] = __builtin_amdgcn_mfma_f32_16x16x32_bf16(a1, b0, acc[1][0], 0, 0, 0);
    acc[1][1] = __builtin_amdgcn_mfma_f32_16x16x32_bf16(a1, b1, acc[1][1], 0, 0, 0);
  }

  #pragma unroll
  for (int ma = 0; ma < 2; ++ma) {
    #pragma unroll
    for (int nb = 0; nb < 2; ++nb) {
      const int n = n0 + (nh + nb) * 16 + l;
      const float bval = bias[n];
      #pragma unroll
      for (int r = 0; r < 4; ++r) {
        const int m = m0 + (mh + ma) * 16 + quad * 4 + r;
        out[(u32)m * DMODEL + n] = acc[ma][nb][r] + bval;
      }
    }
  }
}

extern "C" void kernel_launch(void* const* d_in, const int* in_sizes, int n_in,
                              void* d_out, int out_size, void* d_ws, size_t ws_size,
                              hipStream_t stream) {
  (void)in_sizes; (void)n_in; (void)out_size; (void)ws_size;
  const float* q  = (const float*)d_in[0];
  const float* k  = (const float*)d_in[1];
  const float* v  = (const float*)d_in[2];
  const float* Wq = (const float*)d_in[3];
  const float* bq = (const float*)d_in[4];
  const float* Wk = (const float*)d_in[5];
  const float* bk = (const float*)d_in[6];
  const float* Wv = (const float*)d_in[7];
  const float* bv = (const float*)d_in[8];
  const float* Wo = (const float*)d_in[9];
  const float* bo = (const float*)d_in[10];

  char* ws = (char*)d_ws;
  u16* Qs   = (u16*)(ws);                 // [bh][s][dk] bf16, pre-scaled 1/8 (16 MB)
  u16* Ks   = (u16*)(ws + 16777216);      // [bh][s][dk]
  u16* Vts  = (u16*)(ws + 33554432);      // [bh][dk][s]  (transposed)
  u16* ctx  = (u16*)(ws + 50331648);      // [b][s][h*dk]  (total ws: 64 MB)

  proj_kernel<<<dim3(128, 16, 3), 256, 0, stream>>>(q, k, v, Wq, Wk, Wv,
                                                    bq, bk, bv, Qs, Ks, Vts);
  attn_kernel<<<dim3(32, 64), 256, 0, stream>>>(Qs, Ks, Vts, ctx);
  oproj_kernel<<<dim3(128, 16), 256, 0, stream>>>(ctx, Wo, bo, (float*)d_out);
}

// Round 2
// 1146.305 us; speedup vs baseline: 1.0410x; 1.0410x over previous
//
#include <hip/hip_runtime.h>
#include <stdint.h>

typedef unsigned short u16;
typedef unsigned int u32;
typedef __attribute__((ext_vector_type(8))) short short8;   // 8 x bf16 (4 VGPRs)
typedef __attribute__((ext_vector_type(4))) float f32x4;

#define DEVI static __device__ __forceinline__

#define S_LEN 2048
#define DMODEL 1024
#define NHEAD 16
#define DK 64
#define NEG_INF (-__builtin_inff())
// u = bitcast((bits>>9)|0x3f800000)-1; boundary 0.9f = 7549747/2^23
// keep:   u > 0.9  <=> bits >= 7549748*512
// dropout keep: u < 0.9  <=> bits <  7549747*512
#define KEEPC 3865470976u
#define DROPC 3865470464u

DEVI u16 f2bf(float f) {
  u32 u = __builtin_bit_cast(u32, f);
  u32 r = u + 0x7fffu + ((u >> 16) & 1u);   // RNE
  return (u16)(r >> 16);
}

DEVI short8 cvt8(float4 a, float4 b) {
  short8 r;
  r[0] = (short)f2bf(a.x); r[1] = (short)f2bf(a.y);
  r[2] = (short)f2bf(a.z); r[3] = (short)f2bf(a.w);
  r[4] = (short)f2bf(b.x); r[5] = (short)f2bf(b.y);
  r[6] = (short)f2bf(b.z); r[7] = (short)f2bf(b.w);
  return r;
}

// JAX threefry2x32 (20 rounds), partitionable draw (default since jax 0.4.36):
// key (0,key), ctr (0,i), bits = o0 ^ o1. key is compile-time const at call
// sites -> K2 and injections fold. Validated bit-exact in rounds 2/3.
DEVI u32 tf_bits(u32 key, u32 i) {
  const u32 K2 = key ^ 0x1BD11BDAu;
  u32 x0 = 0u, x1 = i + key;
#define TFR(r) { x0 += x1; x1 = __builtin_rotateleft32(x1, r); x1 ^= x0; }
  TFR(13) TFR(15) TFR(26) TFR(6)  x0 += key; x1 += K2 + 1u;
  TFR(17) TFR(29) TFR(16) TFR(24) x0 += K2;  x1 += 2u;
  TFR(13) TFR(15) TFR(26) TFR(6)  /*x0+=0*/  x1 += key + 3u;
  TFR(17) TFR(29) TFR(16) TFR(24) x0 += key; x1 += K2 + 4u;
  TFR(13) TFR(15) TFR(26) TFR(6)  x0 += K2;  x1 += 5u;
#undef TFR
  return x0 ^ x1;
}

// ---------------- QKV projection GEMM (x @ W.T + b), fp32 in, bf16 MFMA ----------------
// 64x64 tile / block, 4 waves (2x2), each wave 32x32 via 4 C-frags.
// LDS frag-major: chunk c = fragblk*64+lane holds T[row=fragblk*16+(lane&15)][k=(lane>>4)*8..+7]
__global__ __launch_bounds__(256) void proj_kernel(
    const float* __restrict__ Xq, const float* __restrict__ Xk, const float* __restrict__ Xv,
    const float* __restrict__ Wq, const float* __restrict__ Wk, const float* __restrict__ Wv,
    const float* __restrict__ bq, const float* __restrict__ bk, const float* __restrict__ bv,
    u16* __restrict__ Qo, u16* __restrict__ Ko, u16* __restrict__ Vto)
{
  const int z = blockIdx.z;
  const float* X = (z == 0) ? Xq : (z == 1) ? Xk : Xv;
  const float* W = (z == 0) ? Wq : (z == 1) ? Wk : Wv;
  const float* bias = (z == 0) ? bq : (z == 1) ? bk : bv;
  const int m0 = blockIdx.x * 64, n0 = blockIdx.y * 64;
  const int tid = threadIdx.x, w = tid >> 6, lane = tid & 63, l = lane & 15, quad = lane >> 4;

  __shared__ __align__(16) u16 lsA[2048], lsB[2048];

  const int srow = tid >> 2, skp = tid & 3;
  const int sc = ((srow >> 4) * 64 + skp * 16 + (srow & 15)) * 8;
  const float* gA = X + (u32)(m0 + srow) * DMODEL + skp * 8;
  const float* gB = W + (u32)(n0 + srow) * DMODEL + skp * 8;

  f32x4 acc[2][2] = {};
  const int mh = (w >> 1) * 2, nh = (w & 1) * 2;

  for (int k0 = 0; k0 < DMODEL; k0 += 32) {
    short8 av  = cvt8(*(const float4*)(gA + k0), *(const float4*)(gA + k0 + 4));
    short8 bv8 = cvt8(*(const float4*)(gB + k0), *(const float4*)(gB + k0 + 4));
    __syncthreads();
    *(short8*)(lsA + sc) = av;
    *(short8*)(lsB + sc) = bv8;
    __syncthreads();
    short8 a0 = *(const short8*)(lsA + ((mh + 0) * 64 + lane) * 8);
    short8 a1 = *(const short8*)(lsA + ((mh + 1) * 64 + lane) * 8);
    short8 b0 = *(const short8*)(lsB + ((nh + 0) * 64 + lane) * 8);
    short8 b1 = *(const short8*)(lsB + ((nh + 1) * 64 + lane) * 8);
    acc[0][0] = __builtin_amdgcn_mfma_f32_16x16x32_bf16(a0, b0, acc[0][0], 0, 0, 0);
    acc[0][1] = __builtin_amdgcn_mfma_f32_16x16x32_bf16(a0, b1, acc[0][1], 0, 0, 0);
    acc[1][0] = __builtin_amdgcn_mfma_f32_16x16x32_bf16(a1, b0, acc[1][0], 0, 0, 0);
    acc[1][1] = __builtin_amdgcn_mfma_f32_16x16x32_bf16(a1, b1, acc[1][1], 0, 0, 0);
  }

  #pragma unroll
  for (int ma = 0; ma < 2; ++ma) {
    #pragma unroll
    for (int nb = 0; nb < 2; ++nb) {
      const int n = n0 + (nh + nb) * 16 + l;
      const float bval = bias[n];
      const int h = n >> 6, d = n & 63;
      #pragma unroll
      for (int r = 0; r < 4; ++r) {
        const int m = m0 + (mh + ma) * 16 + quad * 4 + r;
        float val = acc[ma][nb][r] + bval;
        if (z == 0) val *= 0.125f;              // fold 1/sqrt(dk) into Q
        const int b = m >> 11, s = m & 2047;
        if (z == 0)      Qo [((u32)(b * NHEAD + h) * S_LEN + s) * DK + d] = f2bf(val);
        else if (z == 1) Ko [((u32)(b * NHEAD + h) * S_LEN + s) * DK + d] = f2bf(val);
        else             Vto[((u32)(b * NHEAD + h) * DK + d) * S_LEN + s] = f2bf(val); // V transposed
      }
    }
  }
}

// ---------------- flash attention with INLINE threefry mask + dropout ----------------
// Masks are generated per-lane in exactly the MFMA C-layout positions this lane
// owns: rows quad*4+r, cols c*16+(lane&15). Draw index i = (bh*2048+q)*2048+k.
// Bit s = c*4+r in m16/d16. No mask memory traffic, no cross-lane machinery.
//
// LDS plan (16 KB): KPf holds K frags during QK^T, then is reused as per-wave
// P staging (K fully consumed into sc4 by then). NO __launch_bounds__ min-wave
// forcing: round-1 showed (256,8) halves arch VGPRs to 32 and spills ~600 MB
// of scratch traffic. Let the allocator pick (64 arch + AGPR accums).
//
// Staging conflict fix (round 2): each wave WRITES 64 consecutive LDS chunks
// (chunk = tid / tid+256) -- linear b128, conflict-free, identical pattern to
// the frag reads. The thread->global mapping is the layout-map inverse:
//   K chunk c: key = ((c>>6)&3)*16 + (c&15), kslot = (c>>8)*4 + ((c>>4)&3)
//   V chunk c: d   = ((c>>7)&3)*16 + (c&15), sslot = ((c>>6)&1)*4 + ((c>>4)&3)
// Per wave the K loads cover a dense 2KB row-block; V loads cover full 64B
// segments of 16 rows. Frag-read indices unchanged.
__global__ __launch_bounds__(256) void attn_kernel(
    const u16* __restrict__ Qs, const u16* __restrict__ Ks, const u16* __restrict__ Vts,
    u16* __restrict__ ctx)
{
  const int qb = blockIdx.x, bh = blockIdx.y;
  const int tid = threadIdx.x, w = tid >> 6, lane = tid & 63, l = lane & 15, quad = lane >> 4;

  __shared__ __align__(16) u16 KPf[4096];       // 8 KB: K frags, then per-wave P
  __shared__ __align__(16) u16 Vf[4096];        // 8 KB

  // Q A-frags, preloaded (Q pre-scaled by 1/8)
  const int qrow0 = qb * 64 + w * 16;
  const u32 qbase = (u32)(bh * S_LEN + qrow0 + l) * DK + quad * 8;
  const short8 qa0 = *(const short8*)(Qs + qbase);
  const short8 qa1 = *(const short8*)(Qs + qbase + 32);

  // per-lane RNG base: rows start at qrow0+quad*4, col offset l (within tile)
  u32 ibase = ((u32)bh * 2048u + (u32)(qrow0 + quad * 4)) * 2048u + (u32)l;

  f32x4 o[4] = {};
  float mr[4] = {NEG_INF, NEG_INF, NEG_INF, NEG_INF};
  float lr[4] = {0.f, 0.f, 0.f, 0.f};

  // ---- staging maps: LDS chunk = tid (and tid+256), global derived by inverse map ----
  // K: thread loads row kA, k-chunks kdp and kdp+4 (bytes [kdp*16, +16) and +64)
  const int kA  = ((tid >> 6) & 3) * 16 + (tid & 15);
  const int kdp = (tid >> 4) & 3;
  const u32 gk  = (u32)(bh * S_LEN + kA) * DK + kdp * 8;
  // V: thread loads rows vd and vd+32 at s-slot vsp
  const int vd  = ((tid >> 7) & 1) * 16 + (tid & 15);
  const int vsp = ((tid >> 6) & 1) * 4 + ((tid >> 4) & 3);
  const u32 gvA = (u32)(bh * DK + vd) * S_LEN + vsp * 8;
  const u32 gvB = (u32)(bh * DK + vd + 32) * S_LEN + vsp * 8;

  // P staging addresses (swizzled). Write chunk c = kb*16 + (quad*4+r):
  //   u16 idx = c*8 + j, with idx bit3 ^= (quad>>1), bit4 ^= hi (hi = kb&1 = l>>3).
  const int hi = l >> 3, j = l & 7;
  const int pxor = ((quad >> 1) << 3) | (hi << 4);
  const int pb = (hi * 128 + quad * 32 + j) ^ pxor;     // r==0 base; bits 3,4 free for r
  const int prd = (lane * 8) ^ (lane & 24);             // swizzled read chunk offset
  u16* const pw = KPf + w * 1024;

  for (int kt = 0; kt < 32; ++kt) {
    const u32 ko = (u32)kt * 64u;
    short8 k0v = *(const short8*)(Ks + gk + ko * DK);        // k-lo half
    short8 k1v = *(const short8*)(Ks + gk + ko * DK + 32);   // k-hi half
    short8 v0v = *(const short8*)(Vts + gvA + ko);
    short8 v1v = *(const short8*)(Vts + gvB + ko);

    // ---- inline RNG: 16 independent keep draws (ILP), then sparse dropout ----
    u32 m16 = 0;
    #pragma unroll
    for (int c = 0; c < 4; ++c) {
      #pragma unroll
      for (int r = 0; r < 4; ++r) {
        m16 |= (u32)(tf_bits(42u, ibase + (u32)(r * 2048 + c * 16)) >= KEEPC) << (c * 4 + r);
      }
    }
    u32 d16 = 0, mm = m16;
    while (mm) {
      const u32 s = (u32)__builtin_ctz(mm); mm &= mm - 1u;
      const u32 ii = ibase + (s & 3u) * 2048u + (s >> 2) * 16u;
      d16 |= (u32)(tf_bits(7u, ii) < DROPC) << s;
    }
    ibase += 64u;

    __syncthreads();                    // prev iter's P/V reads done
    *(short8*)(KPf + tid * 8) = k0v;            // chunk tid        (linear, conflict-free)
    *(short8*)(KPf + 2048 + tid * 8) = k1v;     // chunk tid+256
    *(short8*)(Vf + tid * 8) = v0v;
    *(short8*)(Vf + 2048 + tid * 8) = v1v;
    __syncthreads();

    // S = Q K^T (16q x 64keys per wave)
    f32x4 sc4[4];
    #pragma unroll
    for (int nc = 0; nc < 4; ++nc) {
      short8 kb0 = *(const short8*)(KPf + (nc * 64 + lane) * 8);
      short8 kb1 = *(const short8*)(KPf + ((4 + nc) * 64 + lane) * 8);
      f32x4 zz = {0.f, 0.f, 0.f, 0.f};
      zz = __builtin_amdgcn_mfma_f32_16x16x32_bf16(qa0, kb0, zz, 0, 0, 0);
      sc4[nc] = __builtin_amdgcn_mfma_f32_16x16x32_bf16(qa1, kb1, zz, 0, 0, 0);
    }

    __syncthreads();                    // K fully consumed -> KPf reusable as P

    #pragma unroll
    for (int r = 0; r < 4; ++r) {
      float v0 = ((m16 >> (r + 0))  & 1u) ? sc4[0][r] : NEG_INF;
      float v1 = ((m16 >> (r + 4))  & 1u) ? sc4[1][r] : NEG_INF;
      float v2 = ((m16 >> (r + 8))  & 1u) ? sc4[2][r] : NEG_INF;
      float v3 = ((m16 >> (r + 12)) & 1u) ? sc4[3][r] : NEG_INF;
      float mx = fmaxf(fmaxf(v0, v1), fmaxf(v2, v3));
      mx = fmaxf(mx, __shfl_xor(mx, 1));
      mx = fmaxf(mx, __shfl_xor(mx, 2));
      mx = fmaxf(mx, __shfl_xor(mx, 4));
      mx = fmaxf(mx, __shfl_xor(mx, 8));
      const float mn = fmaxf(mr[r], mx);
      const float alpha = (mn == NEG_INF) ? 1.f : __expf(mr[r] - mn);
      mr[r] = mn;
      const float p0 = (v0 == NEG_INF) ? 0.f : __expf(v0 - mn);
      const float p1 = (v1 == NEG_INF) ? 0.f : __expf(v1 - mn);
      const float p2 = (v2 == NEG_INF) ? 0.f : __expf(v2 - mn);
      const float p3 = (v3 == NEG_INF) ? 0.f : __expf(v3 - mn);
      float rs = p0 + p1 + p2 + p3;
      rs += __shfl_xor(rs, 1);
      rs += __shfl_xor(rs, 2);
      rs += __shfl_xor(rs, 4);
      rs += __shfl_xor(rs, 8);
      lr[r] = alpha * lr[r] + rs;
      o[0][r] = o[0][r] * alpha; o[1][r] = o[1][r] * alpha;
      o[2][r] = o[2][r] * alpha; o[3][r] = o[3][r] * alpha;
      // dropout (denominator uses undropped p; numerator uses p*dbit/0.9)
      const float pd0 = ((d16 >> (r + 0))  & 1u) ? p0 * (1.f / 0.9f) : 0.f;
      const float pd1 = ((d16 >> (r + 4))  & 1u) ? p1 * (1.f / 0.9f) : 0.f;
      const float pd2 = ((d16 >> (r + 8))  & 1u) ? p2 * (1.f / 0.9f) : 0.f;
      const float pd3 = ((d16 >> (r + 12)) & 1u) ? p3 * (1.f / 0.9f) : 0.f;
      // write P in A-frag layout (bank-conflict-free via XOR swizzle)
      const int pi = pb ^ (r * 8);
      pw[pi      ] = f2bf(pd0);   // keys  0..15
      pw[pi + 256] = f2bf(pd1);   // keys 16..31
      pw[pi + 512] = f2bf(pd2);   // keys 32..47
      pw[pi + 768] = f2bf(pd3);   // keys 48..63
    }
    // same-wave LDS round-trip: read P as A-frags (swizzled chunk order)
    short8 pa0 = *(const short8*)(pw + prd);
    short8 pa1 = *(const short8*)(pw + 512 + prd);
    #pragma unroll
    for (int nd = 0; nd < 4; ++nd) {
      short8 vb0 = *(const short8*)(Vf + ((nd * 2 + 0) * 64 + lane) * 8);
      short8 vb1 = *(const short8*)(Vf + ((nd * 2 + 1) * 64 + lane) * 8);
      o[nd] = __builtin_amdgcn_mfma_f32_16x16x32_bf16(pa0, vb0, o[nd], 0, 0, 0);
      o[nd] = __builtin_amdgcn_mfma_f32_16x16x32_bf16(pa1, vb1, o[nd], 0, 0, 0);
    }
  }

  const int b = bh >> 4, h = bh & 15;
  #pragma unroll
  for (int r = 0; r < 4; ++r) {
    const float inv = 1.f / lr[r];
    const int qrow = qb * 64 + w * 16 + quad * 4 + r;
    const u32 ob = (u32)(b * S_LEN + qrow) * DMODEL + h * DK;
    ctx[ob + 0  + l] = f2bf(o[0][r] * inv);
    ctx[ob + 16 + l] = f2bf(o[1][r] * inv);
    ctx[ob + 32 + l] = f2bf(o[2][r] * inv);
    ctx[ob + 48 + l] = f2bf(o[3][r] * inv);
  }
}

// ---------------- output projection (ctx @ Wo.T + bo), bf16 A, fp32 B-in, fp32 out ----------------
__global__ __launch_bounds__(256) void oproj_kernel(
    const u16* __restrict__ X, const float* __restrict__ W, const float* __restrict__ bias,
    float* __restrict__ out)
{
  const int m0 = blockIdx.x * 64, n0 = blockIdx.y * 64;
  const int tid = threadIdx.x, w = tid >> 6, lane = tid & 63, l = lane & 15, quad = lane >> 4;

  __shared__ __align__(16) u16 lsA[2048], lsB[2048];

  const int srow = tid >> 2, skp = tid & 3;
  const int sc = ((srow >> 4) * 64 + skp * 16 + (srow & 15)) * 8;
  const u16*  gA = X + (u32)(m0 + srow) * DMODEL + skp * 8;
  const float* gB = W + (u32)(n0 + srow) * DMODEL + skp * 8;

  f32x4 acc[2][2] = {};
  const int mh = (w >> 1) * 2, nh = (w & 1) * 2;

  for (int k0 = 0; k0 < DMODEL; k0 += 32) {
    short8 av  = *(const short8*)(gA + k0);
    short8 bv8 = cvt8(*(const float4*)(gB + k0), *(const float4*)(gB + k0 + 4));
    __syncthreads();
    *(short8*)(lsA + sc) = av;
    *(short8*)(lsB + sc) = bv8;
    __syncthreads();
    short8 a0 = *(const short8*)(lsA + ((mh + 0) * 64 + lane) * 8);
    short8 a1 = *(const short8*)(lsA + ((mh + 1) * 64 + lane) * 8);
    short8 b0 = *(const short8*)(lsB + ((nh + 0) * 64 + lane) * 8);
    short8 b1 = *(const short8*)(lsB + ((nh + 1) * 64 + lane) * 8);
    acc[0][0] = __builtin_amdgcn_mfma_f32_16x16x32_bf16(a0, b0, acc[0][0], 0, 0, 0);
    acc[0][1] = __builtin_amdgcn_mfma_f32_16x16x32_bf16(a0, b1, acc[0][1], 0, 0, 0);
    acc[1][0] = __builtin_amdgcn_mfma_f32_16x16x32_bf16(a1, b0, acc[1][0], 0, 0, 0);
    acc[1][1] = __builtin_amdgcn_mfma_f32_16x16x32_bf16(a1, b1, acc[1][1], 0, 0, 0);
  }

  #pragma unroll
  for (int ma = 0; ma < 2; ++ma) {
    #pragma unroll
    for (int nb = 0; nb < 2; ++nb) {
      const int n = n0 + (nh + nb) * 16 + l;
      const float bval = bias[n];
      #pragma unroll
      for (int r = 0; r < 4; ++r) {
        const int m = m0 + (mh + ma) * 16 + quad * 4 + r;
        out[(u32)m * DMODEL + n] = acc[ma][nb][r] + bval;
      }
    }
  }
}

extern "C" void kernel_launch(void* const* d_in, const int* in_sizes, int n_in,
                              void* d_out, int out_size, void* d_ws, size_t ws_size,
                              hipStream_t stream) {
  (void)in_sizes; (void)n_in; (void)out_size; (void)ws_size;
  const float* q  = (const float*)d_in[0];
  const float* k  = (const float*)d_in[1];
  const float* v  = (const float*)d_in[2];
  const float* Wq = (const float*)d_in[3];
  const float* bq = (const float*)d_in[4];
  const float* Wk = (const float*)d_in[5];
  const float* bk = (const float*)d_in[6];
  const float* Wv = (const float*)d_in[7];
  const float* bv = (const float*)d_in[8];
  const float* Wo = (const float*)d_in[9];
  const float* bo = (const float*)d_in[10];

  char* ws = (char*)d_ws;
  u16* Qs   = (u16*)(ws);                 // [bh][s][dk] bf16, pre-scaled 1/8 (16 MB)
  u16* Ks   = (u16*)(ws + 16777216);      // [bh][s][dk]
  u16* Vts  = (u16*)(ws + 33554432);      // [bh][dk][s]  (transposed)
  u16* ctx  = (u16*)(ws + 50331648);      // [b][s][h*dk]  (total ws: 64 MB)

  proj_kernel<<<dim3(128, 16, 3), 256, 0, stream>>>(q, k, v, Wq, Wk, Wv,
                                                    bq, bk, bv, Qs, Ks, Vts);
  attn_kernel<<<dim3(32, 64), 256, 0, stream>>>(Qs, Ks, Vts, ctx);
  oproj_kernel<<<dim3(128, 16), 256, 0, stream>>>(ctx, Wo, bo, (float*)d_out);
}

// Round 3
// 1120.288 us; speedup vs baseline: 1.0652x; 1.0232x over previous
//
#include <hip/hip_runtime.h>
#include <stdint.h>

typedef unsigned short u16;
typedef unsigned int u32;
typedef __attribute__((ext_vector_type(8))) short short8;   // 8 x bf16 (4 VGPRs)
typedef __attribute__((ext_vector_type(4))) float f32x4;

#define DEVI static __device__ __forceinline__

#define S_LEN 2048
#define DMODEL 1024
#define NHEAD 16
#define DK 64
#define NEG_INF (-__builtin_inff())
// u = bitcast((bits>>9)|0x3f800000)-1; boundary 0.9f = 7549747/2^23
// keep:   u > 0.9  <=> bits >= 7549748*512
// dropout keep: u < 0.9  <=> bits <  7549747*512
#define KEEPC 3865470976u
#define DROPC 3865470464u

DEVI u16 f2bf(float f) {
  u32 u = __builtin_bit_cast(u32, f);
  u32 r = u + 0x7fffu + ((u >> 16) & 1u);   // RNE
  return (u16)(r >> 16);
}

DEVI short8 cvt8(float4 a, float4 b) {
  short8 r;
  r[0] = (short)f2bf(a.x); r[1] = (short)f2bf(a.y);
  r[2] = (short)f2bf(a.z); r[3] = (short)f2bf(a.w);
  r[4] = (short)f2bf(b.x); r[5] = (short)f2bf(b.y);
  r[6] = (short)f2bf(b.z); r[7] = (short)f2bf(b.w);
  return r;
}

// JAX threefry2x32 (20 rounds), partitionable draw (default since jax 0.4.36):
// key (0,key), ctr (0,i), bits = o0 ^ o1. key is compile-time const at call
// sites -> K2 and injections fold. Validated bit-exact in rounds 2/3.
DEVI u32 tf_bits(u32 key, u32 i) {
  const u32 K2 = key ^ 0x1BD11BDAu;
  u32 x0 = 0u, x1 = i + key;
#define TFR(r) { x0 += x1; x1 = __builtin_rotateleft32(x1, r); x1 ^= x0; }
  TFR(13) TFR(15) TFR(26) TFR(6)  x0 += key; x1 += K2 + 1u;
  TFR(17) TFR(29) TFR(16) TFR(24) x0 += K2;  x1 += 2u;
  TFR(13) TFR(15) TFR(26) TFR(6)  /*x0+=0*/  x1 += key + 3u;
  TFR(17) TFR(29) TFR(16) TFR(24) x0 += key; x1 += K2 + 4u;
  TFR(13) TFR(15) TFR(26) TFR(6)  x0 += K2;  x1 += 5u;
#undef TFR
  return x0 ^ x1;
}

// ---------------- QKV projection GEMM (x @ W.T + b), fp32 in, bf16 MFMA ----------------
// 64x64 tile / block, 4 waves (2x2), each wave 32x32 via 4 C-frags.
// LDS frag-major: chunk c = fragblk*64+lane holds T[row=fragblk*16+(lane&15)][k=(lane>>4)*8..+7]
__global__ __launch_bounds__(256) void proj_kernel(
    const float* __restrict__ Xq, const float* __restrict__ Xk, const float* __restrict__ Xv,
    const float* __restrict__ Wq, const float* __restrict__ Wk, const float* __restrict__ Wv,
    const float* __restrict__ bq, const float* __restrict__ bk, const float* __restrict__ bv,
    u16* __restrict__ Qo, u16* __restrict__ Ko, u16* __restrict__ Vto)
{
  const int z = blockIdx.z;
  const float* X = (z == 0) ? Xq : (z == 1) ? Xk : Xv;
  const float* W = (z == 0) ? Wq : (z == 1) ? Wk : Wv;
  const float* bias = (z == 0) ? bq : (z == 1) ? bk : bv;
  const int m0 = blockIdx.x * 64, n0 = blockIdx.y * 64;
  const int tid = threadIdx.x, w = tid >> 6, lane = tid & 63, l = lane & 15, quad = lane >> 4;

  __shared__ __align__(16) u16 lsA[2048], lsB[2048];

  const int srow = tid >> 2, skp = tid & 3;
  const int sc = ((srow >> 4) * 64 + skp * 16 + (srow & 15)) * 8;
  const float* gA = X + (u32)(m0 + srow) * DMODEL + skp * 8;
  const float* gB = W + (u32)(n0 + srow) * DMODEL + skp * 8;

  f32x4 acc[2][2] = {};
  const int mh = (w >> 1) * 2, nh = (w & 1) * 2;

  for (int k0 = 0; k0 < DMODEL; k0 += 32) {
    short8 av  = cvt8(*(const float4*)(gA + k0), *(const float4*)(gA + k0 + 4));
    short8 bv8 = cvt8(*(const float4*)(gB + k0), *(const float4*)(gB + k0 + 4));
    __syncthreads();
    *(short8*)(lsA + sc) = av;
    *(short8*)(lsB + sc) = bv8;
    __syncthreads();
    short8 a0 = *(const short8*)(lsA + ((mh + 0) * 64 + lane) * 8);
    short8 a1 = *(const short8*)(lsA + ((mh + 1) * 64 + lane) * 8);
    short8 b0 = *(const short8*)(lsB + ((nh + 0) * 64 + lane) * 8);
    short8 b1 = *(const short8*)(lsB + ((nh + 1) * 64 + lane) * 8);
    acc[0][0] = __builtin_amdgcn_mfma_f32_16x16x32_bf16(a0, b0, acc[0][0], 0, 0, 0);
    acc[0][1] = __builtin_amdgcn_mfma_f32_16x16x32_bf16(a0, b1, acc[0][1], 0, 0, 0);
    acc[1][0] = __builtin_amdgcn_mfma_f32_16x16x32_bf16(a1, b0, acc[1][0], 0, 0, 0);
    acc[1][1] = __builtin_amdgcn_mfma_f32_16x16x32_bf16(a1, b1, acc[1][1], 0, 0, 0);
  }

  #pragma unroll
  for (int ma = 0; ma < 2; ++ma) {
    #pragma unroll
    for (int nb = 0; nb < 2; ++nb) {
      const int n = n0 + (nh + nb) * 16 + l;
      const float bval = bias[n];
      const int h = n >> 6, d = n & 63;
      #pragma unroll
      for (int r = 0; r < 4; ++r) {
        const int m = m0 + (mh + ma) * 16 + quad * 4 + r;
        float val = acc[ma][nb][r] + bval;
        if (z == 0) val *= 0.125f;              // fold 1/sqrt(dk) into Q
        const int b = m >> 11, s = m & 2047;
        if (z == 0)      Qo [((u32)(b * NHEAD + h) * S_LEN + s) * DK + d] = f2bf(val);
        else if (z == 1) Ko [((u32)(b * NHEAD + h) * S_LEN + s) * DK + d] = f2bf(val);
        else             Vto[((u32)(b * NHEAD + h) * DK + d) * S_LEN + s] = f2bf(val); // V transposed
      }
    }
  }
}

// ---------------- flash attention with INLINE threefry mask + dropout ----------------
// Masks are generated per-lane in exactly the MFMA C-layout positions this lane
// owns: rows quad*4+r, cols c*16+(lane&15). Draw index i = (bh*2048+q)*2048+k.
// Bit s = c*4+r in m16/d16. No mask memory traffic.
//
// Round-3 change: wave-BALANCED dropout. The old per-lane while(mm) loop ran
// max-popcount-over-wave (~6.5) full threefry draws; the mean useful work is
// only 1.6. Now the wave's kept positions (~102 of 1024) are compacted into a
// dense LDS list (shfl prefix scan), every lane computes ceil(total/64)=2
// draws from the list, and the bits are routed back. Same-wave LDS round trip
// needs no __syncthreads (same idiom as the P-frag round trip below).
__global__ __launch_bounds__(256) void attn_kernel(
    const u16* __restrict__ Qs, const u16* __restrict__ Ks, const u16* __restrict__ Vts,
    u16* __restrict__ ctx)
{
  const int qb = blockIdx.x, bh = blockIdx.y;
  const int tid = threadIdx.x, w = tid >> 6, lane = tid & 63, l = lane & 15, quad = lane >> 4;

  __shared__ __align__(16) u16 KPf[4096];       // 8 KB: K frags, then per-wave P
  __shared__ __align__(16) u16 Vf[4096];        // 8 KB
  __shared__ __align__(16) u16 dbuf[1024];      // 2 KB: per-wave 256-slot dropout worklist

  // Q A-frags, preloaded (Q pre-scaled by 1/8)
  const int qrow0 = qb * 64 + w * 16;
  const u32 qbase = (u32)(bh * S_LEN + qrow0 + l) * DK + quad * 8;
  const short8 qa0 = *(const short8*)(Qs + qbase);
  const short8 qa1 = *(const short8*)(Qs + qbase + 32);

  // per-lane RNG base: rows start at qrow0+quad*4, col offset l (within tile)
  u32 ibase = ((u32)bh * 2048u + (u32)(qrow0 + quad * 4)) * 2048u + (u32)l;
  // wave-uniform tile base for worker-side index reconstruction
  const u32 wb0 = ((u32)bh * 2048u + (u32)qrow0) * 2048u;
  const int dwb = w * 256;

  f32x4 o[4] = {};
  float mr[4] = {NEG_INF, NEG_INF, NEG_INF, NEG_INF};
  float lr[4] = {0.f, 0.f, 0.f, 0.f};

  // ---- staging maps: LDS chunk = tid (and tid+256), global derived by inverse map ----
  const int kA  = ((tid >> 6) & 3) * 16 + (tid & 15);
  const int kdp = (tid >> 4) & 3;
  const u32 gk  = (u32)(bh * S_LEN + kA) * DK + kdp * 8;
  const int vd  = ((tid >> 7) & 1) * 16 + (tid & 15);
  const int vsp = ((tid >> 6) & 1) * 4 + ((tid >> 4) & 3);
  const u32 gvA = (u32)(bh * DK + vd) * S_LEN + vsp * 8;
  const u32 gvB = (u32)(bh * DK + vd + 32) * S_LEN + vsp * 8;

  // P staging addresses (swizzled, conflict-free)
  const int hi = l >> 3, j = l & 7;
  const int pxor = ((quad >> 1) << 3) | (hi << 4);
  const int pb = (hi * 128 + quad * 32 + j) ^ pxor;     // r==0 base; bits 3,4 free for r
  const int prd = (lane * 8) ^ (lane & 24);             // swizzled read chunk offset
  u16* const pw = KPf + w * 1024;

  for (int kt = 0; kt < 32; ++kt) {
    const u32 ko = (u32)kt * 64u;
    short8 k0v = *(const short8*)(Ks + gk + ko * DK);        // k-lo half
    short8 k1v = *(const short8*)(Ks + gk + ko * DK + 32);   // k-hi half
    short8 v0v = *(const short8*)(Vts + gvA + ko);
    short8 v1v = *(const short8*)(Vts + gvB + ko);

    // ---- inline RNG: 16 independent keep draws (ILP) ----
    u32 m16 = 0;
    #pragma unroll
    for (int c = 0; c < 4; ++c) {
      #pragma unroll
      for (int r = 0; r < 4; ++r) {
        m16 |= (u32)(tf_bits(42u, ibase + (u32)(r * 2048 + c * 16)) >= KEEPC) << (c * 4 + r);
      }
    }
    ibase += 64u;

    // ---- wave-balanced dropout draws ----
    const int cnt = __popc(m16);
    int pre = cnt;
    #pragma unroll
    for (int dlt = 1; dlt < 64; dlt <<= 1) {
      int t = __shfl_up(pre, dlt);
      if (lane >= dlt) pre += t;
    }
    const int total = __shfl(pre, 63);   // wave total kept (~102, max ~145)
    pre -= cnt;                          // exclusive prefix = this lane's first slot
    {
      u32 mm = m16; int jj = pre;
      while (mm) {
        const u32 s = (u32)__builtin_ctz(mm); mm &= mm - 1u;
        dbuf[dwb + jj] = (u16)(((u32)lane << 4) | s);
        ++jj;
      }
    }
    const u32 wb = wb0 + (u32)kt * 64u;
    for (int ws2 = lane; ws2 < total; ws2 += 64) {
      const u32 e = (u32)dbuf[dwb + ws2];
      const u32 oo = e >> 4, ss = e & 15u;
      const u32 ii = wb + ((oo >> 4) * 4u + (ss & 3u)) * 2048u + (oo & 15u) + (ss >> 2) * 16u;
      const u32 bit = (u32)(tf_bits(7u, ii) < DROPC);
      dbuf[dwb + ws2] = (u16)(e | (bit << 15));
    }
    u32 d16 = 0;
    {
      u32 mm = m16; int jj = pre;
      while (mm) {
        const u32 s = (u32)__builtin_ctz(mm); mm &= mm - 1u;
        d16 |= (u32)((dbuf[dwb + jj] >> 15) & 1u) << s;
        ++jj;
      }
    }

    __syncthreads();                    // prev iter's P/V reads done
    *(short8*)(KPf + tid * 8) = k0v;            // chunk tid        (linear, conflict-free)
    *(short8*)(KPf + 2048 + tid * 8) = k1v;     // chunk tid+256
    *(short8*)(Vf + tid * 8) = v0v;
    *(short8*)(Vf + 2048 + tid * 8) = v1v;
    __syncthreads();

    // S = Q K^T (16q x 64keys per wave)
    f32x4 sc4[4];
    #pragma unroll
    for (int nc = 0; nc < 4; ++nc) {
      short8 kb0 = *(const short8*)(KPf + (nc * 64 + lane) * 8);
      short8 kb1 = *(const short8*)(KPf + ((4 + nc) * 64 + lane) * 8);
      f32x4 zz = {0.f, 0.f, 0.f, 0.f};
      zz = __builtin_amdgcn_mfma_f32_16x16x32_bf16(qa0, kb0, zz, 0, 0, 0);
      sc4[nc] = __builtin_amdgcn_mfma_f32_16x16x32_bf16(qa1, kb1, zz, 0, 0, 0);
    }

    __syncthreads();                    // K fully consumed -> KPf reusable as P

    #pragma unroll
    for (int r = 0; r < 4; ++r) {
      float v0 = ((m16 >> (r + 0))  & 1u) ? sc4[0][r] : NEG_INF;
      float v1 = ((m16 >> (r + 4))  & 1u) ? sc4[1][r] : NEG_INF;
      float v2 = ((m16 >> (r + 8))  & 1u) ? sc4[2][r] : NEG_INF;
      float v3 = ((m16 >> (r + 12)) & 1u) ? sc4[3][r] : NEG_INF;
      float mx = fmaxf(fmaxf(v0, v1), fmaxf(v2, v3));
      mx = fmaxf(mx, __shfl_xor(mx, 1));
      mx = fmaxf(mx, __shfl_xor(mx, 2));
      mx = fmaxf(mx, __shfl_xor(mx, 4));
      mx = fmaxf(mx, __shfl_xor(mx, 8));
      const float mn = fmaxf(mr[r], mx);
      const float alpha = (mn == NEG_INF) ? 1.f : __expf(mr[r] - mn);
      mr[r] = mn;
      const float p0 = (v0 == NEG_INF) ? 0.f : __expf(v0 - mn);
      const float p1 = (v1 == NEG_INF) ? 0.f : __expf(v1 - mn);
      const float p2 = (v2 == NEG_INF) ? 0.f : __expf(v2 - mn);
      const float p3 = (v3 == NEG_INF) ? 0.f : __expf(v3 - mn);
      float rs = p0 + p1 + p2 + p3;
      rs += __shfl_xor(rs, 1);
      rs += __shfl_xor(rs, 2);
      rs += __shfl_xor(rs, 4);
      rs += __shfl_xor(rs, 8);
      lr[r] = alpha * lr[r] + rs;
      o[0][r] = o[0][r] * alpha; o[1][r] = o[1][r] * alpha;
      o[2][r] = o[2][r] * alpha; o[3][r] = o[3][r] * alpha;
      // dropout (denominator uses undropped p; numerator uses p*dbit/0.9)
      const float pd0 = ((d16 >> (r + 0))  & 1u) ? p0 * (1.f / 0.9f) : 0.f;
      const float pd1 = ((d16 >> (r + 4))  & 1u) ? p1 * (1.f / 0.9f) : 0.f;
      const float pd2 = ((d16 >> (r + 8))  & 1u) ? p2 * (1.f / 0.9f) : 0.f;
      const float pd3 = ((d16 >> (r + 12)) & 1u) ? p3 * (1.f / 0.9f) : 0.f;
      // write P in A-frag layout (bank-conflict-free via XOR swizzle)
      const int pi = pb ^ (r * 8);
      pw[pi      ] = f2bf(pd0);   // keys  0..15
      pw[pi + 256] = f2bf(pd1);   // keys 16..31
      pw[pi + 512] = f2bf(pd2);   // keys 32..47
      pw[pi + 768] = f2bf(pd3);   // keys 48..63
    }
    // same-wave LDS round-trip: read P as A-frags (swizzled chunk order)
    short8 pa0 = *(const short8*)(pw + prd);
    short8 pa1 = *(const short8*)(pw + 512 + prd);
    #pragma unroll
    for (int nd = 0; nd < 4; ++nd) {
      short8 vb0 = *(const short8*)(Vf + ((nd * 2 + 0) * 64 + lane) * 8);
      short8 vb1 = *(const short8*)(Vf + ((nd * 2 + 1) * 64 + lane) * 8);
      o[nd] = __builtin_amdgcn_mfma_f32_16x16x32_bf16(pa0, vb0, o[nd], 0, 0, 0);
      o[nd] = __builtin_amdgcn_mfma_f32_16x16x32_bf16(pa1, vb1, o[nd], 0, 0, 0);
    }
  }

  const int b = bh >> 4, h = bh & 15;
  #pragma unroll
  for (int r = 0; r < 4; ++r) {
    const float inv = 1.f / lr[r];
    const int qrow = qb * 64 + w * 16 + quad * 4 + r;
    const u32 ob = (u32)(b * S_LEN + qrow) * DMODEL + h * DK;
    ctx[ob + 0  + l] = f2bf(o[0][r] * inv);
    ctx[ob + 16 + l] = f2bf(o[1][r] * inv);
    ctx[ob + 32 + l] = f2bf(o[2][r] * inv);
    ctx[ob + 48 + l] = f2bf(o[3][r] * inv);
  }
}

// ---------------- output projection (ctx @ Wo.T + bo), bf16 A, fp32 B-in, fp32 out ----------------
__global__ __launch_bounds__(256) void oproj_kernel(
    const u16* __restrict__ X, const float* __restrict__ W, const float* __restrict__ bias,
    float* __restrict__ out)
{
  const int m0 = blockIdx.x * 64, n0 = blockIdx.y * 64;
  const int tid = threadIdx.x, w = tid >> 6, lane = tid & 63, l = lane & 15, quad = lane >> 4;

  __shared__ __align__(16) u16 lsA[2048], lsB[2048];

  const int srow = tid >> 2, skp = tid & 3;
  const int sc = ((srow >> 4) * 64 + skp * 16 + (srow & 15)) * 8;
  const u16*  gA = X + (u32)(m0 + srow) * DMODEL + skp * 8;
  const float* gB = W + (u32)(n0 + srow) * DMODEL + skp * 8;

  f32x4 acc[2][2] = {};
  const int mh = (w >> 1) * 2, nh = (w & 1) * 2;

  for (int k0 = 0; k0 < DMODEL; k0 += 32) {
    short8 av  = *(const short8*)(gA + k0);
    short8 bv8 = cvt8(*(const float4*)(gB + k0), *(const float4*)(gB + k0 + 4));
    __syncthreads();
    *(short8*)(lsA + sc) = av;
    *(short8*)(lsB + sc) = bv8;
    __syncthreads();
    short8 a0 = *(const short8*)(lsA + ((mh + 0) * 64 + lane) * 8);
    short8 a1 = *(const short8*)(lsA + ((mh + 1) * 64 + lane) * 8);
    short8 b0 = *(const short8*)(lsB + ((nh + 0) * 64 + lane) * 8);
    short8 b1 = *(const short8*)(lsB + ((nh + 1) * 64 + lane) * 8);
    acc[0][0] = __builtin_amdgcn_mfma_f32_16x16x32_bf16(a0, b0, acc[0][0], 0, 0, 0);
    acc[0][1] = __builtin_amdgcn_mfma_f32_16x16x32_bf16(a0, b1, acc[0][1], 0, 0, 0);
    acc[1][0] = __builtin_amdgcn_mfma_f32_16x16x32_bf16(a1, b0, acc[1][0], 0, 0, 0);
    acc[1][1] = __builtin_amdgcn_mfma_f32_16x16x32_bf16(a1, b1, acc[1][1], 0, 0, 0);
  }

  #pragma unroll
  for (int ma = 0; ma < 2; ++ma) {
    #pragma unroll
    for (int nb = 0; nb < 2; ++nb) {
      const int n = n0 + (nh + nb) * 16 + l;
      const float bval = bias[n];
      #pragma unroll
      for (int r = 0; r < 4; ++r) {
        const int m = m0 + (mh + ma) * 16 + quad * 4 + r;
        out[(u32)m * DMODEL + n] = acc[ma][nb][r] + bval;
      }
    }
  }
}

extern "C" void kernel_launch(void* const* d_in, const int* in_sizes, int n_in,
                              void* d_out, int out_size, void* d_ws, size_t ws_size,
                              hipStream_t stream) {
  (void)in_sizes; (void)n_in; (void)out_size; (void)ws_size;
  const float* q  = (const float*)d_in[0];
  const float* k  = (const float*)d_in[1];
  const float* v  = (const float*)d_in[2];
  const float* Wq = (const float*)d_in[3];
  const float* bq = (const float*)d_in[4];
  const float* Wk = (const float*)d_in[5];
  const float* bk = (const float*)d_in[6];
  const float* Wv = (const float*)d_in[7];
  const float* bv = (const float*)d_in[8];
  const float* Wo = (const float*)d_in[9];
  const float* bo = (const float*)d_in[10];

  char* ws = (char*)d_ws;
  u16* Qs   = (u16*)(ws);                 // [bh][s][dk] bf16, pre-scaled 1/8 (16 MB)
  u16* Ks   = (u16*)(ws + 16777216);      // [bh][s][dk]
  u16* Vts  = (u16*)(ws + 33554432);      // [bh][dk][s]  (transposed)
  u16* ctx  = (u16*)(ws + 50331648);      // [b][s][h*dk]  (total ws: 64 MB)

  proj_kernel<<<dim3(128, 16, 3), 256, 0, stream>>>(q, k, v, Wq, Wk, Wv,
                                                    bq, bk, bv, Qs, Ks, Vts);
  attn_kernel<<<dim3(32, 64), 256, 0, stream>>>(Qs, Ks, Vts, ctx);
  oproj_kernel<<<dim3(128, 16), 256, 0, stream>>>(ctx, Wo, bo, (float*)d_out);
}

// Round 4
// 1111.366 us; speedup vs baseline: 1.0738x; 1.0080x over previous
//
#include <hip/hip_runtime.h>
#include <stdint.h>

typedef unsigned short u16;
typedef unsigned int u32;
typedef __attribute__((ext_vector_type(8))) short short8;   // 8 x bf16 (4 VGPRs)
typedef __attribute__((ext_vector_type(4))) float f32x4;

#define DEVI static __device__ __forceinline__

#define S_LEN 2048
#define DMODEL 1024
#define NHEAD 16
#define DK 64
#define NEG_INF (-__builtin_inff())
// u = bitcast((bits>>9)|0x3f800000)-1; boundary 0.9f = 7549747/2^23
// keep:   u > 0.9  <=> bits >= 7549748*512
// dropout keep: u < 0.9  <=> bits <  7549747*512
#define KEEPC 3865470976u
#define DROPC 3865470464u

DEVI u16 f2bf(float f) {
  u32 u = __builtin_bit_cast(u32, f);
  u32 r = u + 0x7fffu + ((u >> 16) & 1u);   // RNE
  return (u16)(r >> 16);
}

DEVI short8 cvt8(float4 a, float4 b) {
  short8 r;
  r[0] = (short)f2bf(a.x); r[1] = (short)f2bf(a.y);
  r[2] = (short)f2bf(a.z); r[3] = (short)f2bf(a.w);
  r[4] = (short)f2bf(b.x); r[5] = (short)f2bf(b.y);
  r[6] = (short)f2bf(b.z); r[7] = (short)f2bf(b.w);
  return r;
}

// JAX threefry2x32 (20 rounds), partitionable draw (default since jax 0.4.36):
// key (0,key), ctr (0,i), bits = o0 ^ o1. key is compile-time const at call
// sites -> K2 and injections fold. Validated bit-exact in rounds 2/3.
DEVI u32 tf_bits(u32 key, u32 i) {
  const u32 K2 = key ^ 0x1BD11BDAu;
  u32 x0 = 0u, x1 = i + key;
#define TFR(r) { x0 += x1; x1 = __builtin_rotateleft32(x1, r); x1 ^= x0; }
  TFR(13) TFR(15) TFR(26) TFR(6)  x0 += key; x1 += K2 + 1u;
  TFR(17) TFR(29) TFR(16) TFR(24) x0 += K2;  x1 += 2u;
  TFR(13) TFR(15) TFR(26) TFR(6)  /*x0+=0*/  x1 += key + 3u;
  TFR(17) TFR(29) TFR(16) TFR(24) x0 += key; x1 += K2 + 4u;
  TFR(13) TFR(15) TFR(26) TFR(6)  x0 += K2;  x1 += 5u;
#undef TFR
  return x0 ^ x1;
}

// 16 keep draws for one 16q x 64k lane-tile (branch-free; meant to be merged
// by the scheduler into MFMA/ds_read stall regions of the SAME basic block).
DEVI u32 keep16(u32 ib) {
  u32 m16 = 0;
  #pragma unroll
  for (int c = 0; c < 4; ++c) {
    #pragma unroll
    for (int r = 0; r < 4; ++r) {
      m16 |= (u32)(tf_bits(42u, ib + (u32)(r * 2048 + c * 16)) >= KEEPC) << (c * 4 + r);
    }
  }
  return m16;
}

// Wave-balanced dropout draws for the kept positions of m16 (validated r3).
// dwp = this wave's 256-slot LDS worklist. Same-wave LDS round trip, no barrier.
DEVI u32 drop_balanced(u32 m16, u32 wb, int lane, u16* dwp) {
  const int cnt = __popc(m16);
  int pre = cnt;
  #pragma unroll
  for (int dlt = 1; dlt < 64; dlt <<= 1) {
    int t = __shfl_up(pre, dlt);
    if (lane >= dlt) pre += t;
  }
  const int total = __shfl(pre, 63);   // wave total kept (~102, max ~145)
  pre -= cnt;                          // exclusive prefix = this lane's first slot
  {
    u32 mm = m16; int jj = pre;
    while (mm) {
      const u32 s = (u32)__builtin_ctz(mm); mm &= mm - 1u;
      dwp[jj] = (u16)(((u32)lane << 4) | s);
      ++jj;
    }
  }
  for (int ws2 = lane; ws2 < total; ws2 += 64) {
    const u32 e = (u32)dwp[ws2];
    const u32 oo = e >> 4, ss = e & 15u;
    const u32 ii = wb + ((oo >> 4) * 4u + (ss & 3u)) * 2048u + (oo & 15u) + (ss >> 2) * 16u;
    dwp[ws2] = (u16)(e | ((u32)(tf_bits(7u, ii) < DROPC) << 15));
  }
  u32 d16 = 0;
  {
    u32 mm = m16; int jj = pre;
    while (mm) {
      const u32 s = (u32)__builtin_ctz(mm); mm &= mm - 1u;
      d16 |= (u32)((dwp[jj] >> 15) & 1u) << s;
      ++jj;
    }
  }
  return d16;
}

// ---------------- QKV projection GEMM (x @ W.T + b), fp32 in, bf16 MFMA ----------------
// 64x64 tile / block, 4 waves (2x2), each wave 32x32 via 4 C-frags.
// LDS frag-major: chunk c = fragblk*64+lane holds T[row=fragblk*16+(lane&15)][k=(lane>>4)*8..+7]
__global__ __launch_bounds__(256) void proj_kernel(
    const float* __restrict__ Xq, const float* __restrict__ Xk, const float* __restrict__ Xv,
    const float* __restrict__ Wq, const float* __restrict__ Wk, const float* __restrict__ Wv,
    const float* __restrict__ bq, const float* __restrict__ bk, const float* __restrict__ bv,
    u16* __restrict__ Qo, u16* __restrict__ Ko, u16* __restrict__ Vto)
{
  const int z = blockIdx.z;
  const float* X = (z == 0) ? Xq : (z == 1) ? Xk : Xv;
  const float* W = (z == 0) ? Wq : (z == 1) ? Wk : Wv;
  const float* bias = (z == 0) ? bq : (z == 1) ? bk : bv;
  const int m0 = blockIdx.x * 64, n0 = blockIdx.y * 64;
  const int tid = threadIdx.x, w = tid >> 6, lane = tid & 63, l = lane & 15, quad = lane >> 4;

  __shared__ __align__(16) u16 lsA[2048], lsB[2048];

  const int srow = tid >> 2, skp = tid & 3;
  const int sc = ((srow >> 4) * 64 + skp * 16 + (srow & 15)) * 8;
  const float* gA = X + (u32)(m0 + srow) * DMODEL + skp * 8;
  const float* gB = W + (u32)(n0 + srow) * DMODEL + skp * 8;

  f32x4 acc[2][2] = {};
  const int mh = (w >> 1) * 2, nh = (w & 1) * 2;

  for (int k0 = 0; k0 < DMODEL; k0 += 32) {
    short8 av  = cvt8(*(const float4*)(gA + k0), *(const float4*)(gA + k0 + 4));
    short8 bv8 = cvt8(*(const float4*)(gB + k0), *(const float4*)(gB + k0 + 4));
    __syncthreads();
    *(short8*)(lsA + sc) = av;
    *(short8*)(lsB + sc) = bv8;
    __syncthreads();
    short8 a0 = *(const short8*)(lsA + ((mh + 0) * 64 + lane) * 8);
    short8 a1 = *(const short8*)(lsA + ((mh + 1) * 64 + lane) * 8);
    short8 b0 = *(const short8*)(lsB + ((nh + 0) * 64 + lane) * 8);
    short8 b1 = *(const short8*)(lsB + ((nh + 1) * 64 + lane) * 8);
    acc[0][0] = __builtin_amdgcn_mfma_f32_16x16x32_bf16(a0, b0, acc[0][0], 0, 0, 0);
    acc[0][1] = __builtin_amdgcn_mfma_f32_16x16x32_bf16(a0, b1, acc[0][1], 0, 0, 0);
    acc[1][0] = __builtin_amdgcn_mfma_f32_16x16x32_bf16(a1, b0, acc[1][0], 0, 0, 0);
    acc[1][1] = __builtin_amdgcn_mfma_f32_16x16x32_bf16(a1, b1, acc[1][1], 0, 0, 0);
  }

  #pragma unroll
  for (int ma = 0; ma < 2; ++ma) {
    #pragma unroll
    for (int nb = 0; nb < 2; ++nb) {
      const int n = n0 + (nh + nb) * 16 + l;
      const float bval = bias[n];
      const int h = n >> 6, d = n & 63;
      #pragma unroll
      for (int r = 0; r < 4; ++r) {
        const int m = m0 + (mh + ma) * 16 + quad * 4 + r;
        float val = acc[ma][nb][r] + bval;
        if (z == 0) val *= 0.125f;              // fold 1/sqrt(dk) into Q
        const int b = m >> 11, s = m & 2047;
        if (z == 0)      Qo [((u32)(b * NHEAD + h) * S_LEN + s) * DK + d] = f2bf(val);
        else if (z == 1) Ko [((u32)(b * NHEAD + h) * S_LEN + s) * DK + d] = f2bf(val);
        else             Vto[((u32)(b * NHEAD + h) * DK + d) * S_LEN + s] = f2bf(val); // V transposed
      }
    }
  }
}

// ---------------- flash attention with INLINE threefry mask + dropout ----------------
// Round-4 change: software pipelining. Real VALU busy is ~45% (the 93% counter
// is a gfx94x-formula fallback assuming 4cy/wave64-instr; gfx950 SIMD-32 does
// 2cy) -- half the runtime is latency/barrier stalls. The RNG for tile kt+1 is
// independent of tile kt, so:
//   - keep-draws(kt+1) are computed inside the QK^T region (fills ds/MFMA waits)
//   - global K/V loads are hoisted one tile ahead (full-iteration latency cover)
//   - dropout-balance(kt+1) runs after PV, off the critical path
//   - NEG_INF cndmasks replaced by one clamp: exp(x - max(mn,-1e37)) is 0 for
//     masked lanes and handles the all-masked row (o=lr=0 so alpha irrelevant)
__global__ __launch_bounds__(256) void attn_kernel(
    const u16* __restrict__ Qs, const u16* __restrict__ Ks, const u16* __restrict__ Vts,
    u16* __restrict__ ctx)
{
  const int qb = blockIdx.x, bh = blockIdx.y;
  const int tid = threadIdx.x, w = tid >> 6, lane = tid & 63, l = lane & 15, quad = lane >> 4;

  __shared__ __align__(16) u16 KPf[4096];       // 8 KB: K frags, then per-wave P
  __shared__ __align__(16) u16 Vf[4096];        // 8 KB
  __shared__ __align__(16) u16 dbuf[1024];      // 2 KB: per-wave 256-slot dropout worklist

  // Q A-frags, preloaded (Q pre-scaled by 1/8)
  const int qrow0 = qb * 64 + w * 16;
  const u32 qbase = (u32)(bh * S_LEN + qrow0 + l) * DK + quad * 8;
  const short8 qa0 = *(const short8*)(Qs + qbase);
  const short8 qa1 = *(const short8*)(Qs + qbase + 32);

  // per-lane RNG base: rows start at qrow0+quad*4, col offset l (within tile)
  u32 ibase = ((u32)bh * 2048u + (u32)(qrow0 + quad * 4)) * 2048u + (u32)l;
  // wave-uniform tile base for worker-side index reconstruction
  const u32 wb0 = ((u32)bh * 2048u + (u32)qrow0) * 2048u;
  u16* const dwp = dbuf + w * 256;

  f32x4 o[4] = {};
  float mr[4] = {NEG_INF, NEG_INF, NEG_INF, NEG_INF};
  float lr[4] = {0.f, 0.f, 0.f, 0.f};

  // ---- staging maps: LDS chunk = tid (and tid+256), global derived by inverse map ----
  const int kA  = ((tid >> 6) & 3) * 16 + (tid & 15);
  const int kdp = (tid >> 4) & 3;
  const u32 gk  = (u32)(bh * S_LEN + kA) * DK + kdp * 8;
  const int vd  = ((tid >> 7) & 1) * 16 + (tid & 15);
  const int vsp = ((tid >> 6) & 1) * 4 + ((tid >> 4) & 3);
  const u32 gvA = (u32)(bh * DK + vd) * S_LEN + vsp * 8;
  const u32 gvB = (u32)(bh * DK + vd + 32) * S_LEN + vsp * 8;

  // P staging addresses (swizzled, conflict-free)
  const int hi = l >> 3, j = l & 7;
  const int pxor = ((quad >> 1) << 3) | (hi << 4);
  const int pb = (hi * 128 + quad * 32 + j) ^ pxor;     // r==0 base; bits 3,4 free for r
  const int prd = (lane * 8) ^ (lane & 24);             // swizzled read chunk offset
  u16* const pw = KPf + w * 1024;

  // ---- prologue: loads + RNG for tile 0 ----
  short8 k0v = *(const short8*)(Ks + gk);
  short8 k1v = *(const short8*)(Ks + gk + 32);
  short8 v0v = *(const short8*)(Vts + gvA);
  short8 v1v = *(const short8*)(Vts + gvB);
  u32 m16 = keep16(ibase);
  u32 d16 = drop_balanced(m16, wb0, lane, dwp);
  ibase += 64u;

  for (int kt = 0; kt < 32; ++kt) {
    __syncthreads();                    // prev iter's P/V reads done
    *(short8*)(KPf + tid * 8) = k0v;            // chunk tid        (linear, conflict-free)
    *(short8*)(KPf + 2048 + tid * 8) = k1v;     // chunk tid+256
    *(short8*)(Vf + tid * 8) = v0v;
    *(short8*)(Vf + 2048 + tid * 8) = v1v;
    __syncthreads();

    // issue next tile's loads now: a full iteration of latency cover.
    // kt=31 reads one tile past Ks/Vts ends -- still inside the 64 MB
    // workspace (never staged/used), so no fault and no clamp needed.
    {
      const u32 ko = (u32)(kt + 1) * 64u;
      k0v = *(const short8*)(Ks + gk + ko * DK);
      k1v = *(const short8*)(Ks + gk + ko * DK + 32);
      v0v = *(const short8*)(Vts + gvA + ko);
      v1v = *(const short8*)(Vts + gvB + ko);
    }

    // S = Q K^T (16q x 64keys per wave), with next tile's keep-draws merged
    // into the same region as VALU filler for the ds_read/MFMA waits.
    f32x4 sc4[4];
    #pragma unroll
    for (int nc = 0; nc < 4; ++nc) {
      short8 kb0 = *(const short8*)(KPf + (nc * 64 + lane) * 8);
      short8 kb1 = *(const short8*)(KPf + ((4 + nc) * 64 + lane) * 8);
      f32x4 zz = {0.f, 0.f, 0.f, 0.f};
      zz = __builtin_amdgcn_mfma_f32_16x16x32_bf16(qa0, kb0, zz, 0, 0, 0);
      sc4[nc] = __builtin_amdgcn_mfma_f32_16x16x32_bf16(qa1, kb1, zz, 0, 0, 0);
    }
    const u32 m16n = keep16(ibase);     // tile kt+1 (kt=31: harmless filler)

    __syncthreads();                    // K fully consumed -> KPf reusable as P

    #pragma unroll
    for (int r = 0; r < 4; ++r) {
      float v0 = ((m16 >> (r + 0))  & 1u) ? sc4[0][r] : NEG_INF;
      float v1 = ((m16 >> (r + 4))  & 1u) ? sc4[1][r] : NEG_INF;
      float v2 = ((m16 >> (r + 8))  & 1u) ? sc4[2][r] : NEG_INF;
      float v3 = ((m16 >> (r + 12)) & 1u) ? sc4[3][r] : NEG_INF;
      float mx = fmaxf(fmaxf(v0, v1), fmaxf(v2, v3));
      mx = fmaxf(mx, __shfl_xor(mx, 1));
      mx = fmaxf(mx, __shfl_xor(mx, 2));
      mx = fmaxf(mx, __shfl_xor(mx, 4));
      mx = fmaxf(mx, __shfl_xor(mx, 8));
      const float mn = fmaxf(mr[r], mx);
      const float mnc = fmaxf(mn, -1e37f);        // clamp: exp(-inf-mnc)=0
      const float alpha = __expf(mr[r] - mnc);    // mr=-inf -> 0 (o,lr are 0)
      mr[r] = mn;
      const float p0 = __expf(v0 - mnc);
      const float p1 = __expf(v1 - mnc);
      const float p2 = __expf(v2 - mnc);
      const float p3 = __expf(v3 - mnc);
      float rs = p0 + p1 + p2 + p3;
      rs += __shfl_xor(rs, 1);
      rs += __shfl_xor(rs, 2);
      rs += __shfl_xor(rs, 4);
      rs += __shfl_xor(rs, 8);
      lr[r] = alpha * lr[r] + rs;
      o[0][r] = o[0][r] * alpha; o[1][r] = o[1][r] * alpha;
      o[2][r] = o[2][r] * alpha; o[3][r] = o[3][r] * alpha;
      // dropout (denominator uses undropped p; numerator uses p*dbit/0.9)
      const float pd0 = ((d16 >> (r + 0))  & 1u) ? p0 * (1.f / 0.9f) : 0.f;
      const float pd1 = ((d16 >> (r + 4))  & 1u) ? p1 * (1.f / 0.9f) : 0.f;
      const float pd2 = ((d16 >> (r + 8))  & 1u) ? p2 * (1.f / 0.9f) : 0.f;
      const float pd3 = ((d16 >> (r + 12)) & 1u) ? p3 * (1.f / 0.9f) : 0.f;
      // write P in A-frag layout (bank-conflict-free via XOR swizzle)
      const int pi = pb ^ (r * 8);
      pw[pi      ] = f2bf(pd0);   // keys  0..15
      pw[pi + 256] = f2bf(pd1);   // keys 16..31
      pw[pi + 512] = f2bf(pd2);   // keys 32..47
      pw[pi + 768] = f2bf(pd3);   // keys 48..63
    }
    // same-wave LDS round-trip: read P as A-frags (swizzled chunk order)
    short8 pa0 = *(const short8*)(pw + prd);
    short8 pa1 = *(const short8*)(pw + 512 + prd);
    #pragma unroll
    for (int nd = 0; nd < 4; ++nd) {
      short8 vb0 = *(const short8*)(Vf + ((nd * 2 + 0) * 64 + lane) * 8);
      short8 vb1 = *(const short8*)(Vf + ((nd * 2 + 1) * 64 + lane) * 8);
      o[nd] = __builtin_amdgcn_mfma_f32_16x16x32_bf16(pa0, vb0, o[nd], 0, 0, 0);
      o[nd] = __builtin_amdgcn_mfma_f32_16x16x32_bf16(pa1, vb1, o[nd], 0, 0, 0);
    }

    // dropout-balance for tile kt+1 (off critical path; dbuf is wave-private)
    u32 d16n = 0;
    if (kt < 31) d16n = drop_balanced(m16n, wb0 + (u32)(kt + 1) * 64u, lane, dwp);
    m16 = m16n; d16 = d16n;
    ibase += 64u;
  }

  const int b = bh >> 4, h = bh & 15;
  #pragma unroll
  for (int r = 0; r < 4; ++r) {
    const float inv = 1.f / lr[r];
    const int qrow = qb * 64 + w * 16 + quad * 4 + r;
    const u32 ob = (u32)(b * S_LEN + qrow) * DMODEL + h * DK;
    ctx[ob + 0  + l] = f2bf(o[0][r] * inv);
    ctx[ob + 16 + l] = f2bf(o[1][r] * inv);
    ctx[ob + 32 + l] = f2bf(o[2][r] * inv);
    ctx[ob + 48 + l] = f2bf(o[3][r] * inv);
  }
}

// ---------------- output projection (ctx @ Wo.T + bo), bf16 A, fp32 B-in, fp32 out ----------------
__global__ __launch_bounds__(256) void oproj_kernel(
    const u16* __restrict__ X, const float* __restrict__ W, const float* __restrict__ bias,
    float* __restrict__ out)
{
  const int m0 = blockIdx.x * 64, n0 = blockIdx.y * 64;
  const int tid = threadIdx.x, w = tid >> 6, lane = tid & 63, l = lane & 15, quad = lane >> 4;

  __shared__ __align__(16) u16 lsA[2048], lsB[2048];

  const int srow = tid >> 2, skp = tid & 3;
  const int sc = ((srow >> 4) * 64 + skp * 16 + (srow & 15)) * 8;
  const u16*  gA = X + (u32)(m0 + srow) * DMODEL + skp * 8;
  const float* gB = W + (u32)(n0 + srow) * DMODEL + skp * 8;

  f32x4 acc[2][2] = {};
  const int mh = (w >> 1) * 2, nh = (w & 1) * 2;

  for (int k0 = 0; k0 < DMODEL; k0 += 32) {
    short8 av  = *(const short8*)(gA + k0);
    short8 bv8 = cvt8(*(const float4*)(gB + k0), *(const float4*)(gB + k0 + 4));
    __syncthreads();
    *(short8*)(lsA + sc) = av;
    *(short8*)(lsB + sc) = bv8;
    __syncthreads();
    short8 a0 = *(const short8*)(lsA + ((mh + 0) * 64 + lane) * 8);
    short8 a1 = *(const short8*)(lsA + ((mh + 1) * 64 + lane) * 8);
    short8 b0 = *(const short8*)(lsB + ((nh + 0) * 64 + lane) * 8);
    short8 b1 = *(const short8*)(lsB + ((nh + 1) * 64 + lane) * 8);
    acc[0][0] = __builtin_amdgcn_mfma_f32_16x16x32_bf16(a0, b0, acc[0][0], 0, 0, 0);
    acc[0][1] = __builtin_amdgcn_mfma_f32_16x16x32_bf16(a0, b1, acc[0][1], 0, 0, 0);
    acc[1][0] = __builtin_amdgcn_mfma_f32_16x16x32_bf16(a1, b0, acc[1][0], 0, 0, 0);
    acc[1][1] = __builtin_amdgcn_mfma_f32_16x16x32_bf16(a1, b1, acc[1][1], 0, 0, 0);
  }

  #pragma unroll
  for (int ma = 0; ma < 2; ++ma) {
    #pragma unroll
    for (int nb = 0; nb < 2; ++nb) {
      const int n = n0 + (nh + nb) * 16 + l;
      const float bval = bias[n];
      #pragma unroll
      for (int r = 0; r < 4; ++r) {
        const int m = m0 + (mh + ma) * 16 + quad * 4 + r;
        out[(u32)m * DMODEL + n] = acc[ma][nb][r] + bval;
      }
    }
  }
}

extern "C" void kernel_launch(void* const* d_in, const int* in_sizes, int n_in,
                              void* d_out, int out_size, void* d_ws, size_t ws_size,
                              hipStream_t stream) {
  (void)in_sizes; (void)n_in; (void)out_size; (void)ws_size;
  const float* q  = (const float*)d_in[0];
  const float* k  = (const float*)d_in[1];
  const float* v  = (const float*)d_in[2];
  const float* Wq = (const float*)d_in[3];
  const float* bq = (const float*)d_in[4];
  const float* Wk = (const float*)d_in[5];
  const float* bk = (const float*)d_in[6];
  const float* Wv = (const float*)d_in[7];
  const float* bv = (const float*)d_in[8];
  const float* Wo = (const float*)d_in[9];
  const float* bo = (const float*)d_in[10];

  char* ws = (char*)d_ws;
  u16* Qs   = (u16*)(ws);                 // [bh][s][dk] bf16, pre-scaled 1/8 (16 MB)
  u16* Ks   = (u16*)(ws + 16777216);      // [bh][s][dk]
  u16* Vts  = (u16*)(ws + 33554432);      // [bh][dk][s]  (transposed)
  u16* ctx  = (u16*)(ws + 50331648);      // [b][s][h*dk]  (total ws: 64 MB)

  proj_kernel<<<dim3(128, 16, 3), 256, 0, stream>>>(q, k, v, Wq, Wk, Wv,
                                                    bq, bk, bv, Qs, Ks, Vts);
  attn_kernel<<<dim3(32, 64), 256, 0, stream>>>(Qs, Ks, Vts, ctx);
  oproj_kernel<<<dim3(128, 16), 256, 0, stream>>>(ctx, Wo, bo, (float*)d_out);
}